// Round 1
// baseline (1213.928 us; speedup 1.0000x reference)
//
#include <hip/hip_runtime.h>
#include <hip/hip_bf16.h>

#define B_    32
#define CIN   64
#define HW    56
#define COUT  128
#define M_    256
#define P_    576
#define L_    3136
#define N_    100352

typedef __hip_bfloat16 bf16;

__device__ __forceinline__ float bits2f(unsigned short u){ return __uint_as_float(((unsigned)u)<<16); }

// ---- K0: b2[m] = sum_p C[m][p]^2 -------------------------------------------
__global__ __launch_bounds__(256) void k0_b2(const float* __restrict__ C, float* __restrict__ b2v){
  const int m = threadIdx.x;
  const float4* row = (const float4*)(C + (size_t)m * P_);
  float s = 0.f;
  for (int p = 0; p < P_/4; ++p){ float4 v = row[p]; s += v.x*v.x + v.y*v.y + v.z*v.z + v.w*v.w; }
  b2v[m] = s;
}

// ---- K1: unfold -> A (bf16, [n][p]) + a2[n] --------------------------------
__global__ __launch_bounds__(256) void k1_unfold(const float* __restrict__ x,
                                                 bf16* __restrict__ A,
                                                 float* __restrict__ a2v){
  const int wv   = blockIdx.x * 4 + (threadIdx.x >> 6);
  const int lane = threadIdx.x & 63;              // lane = input channel
  const int b = wv / L_, l = wv % L_;
  const int h = l / HW, w = l % HW;
  const float* xb = x + ((size_t)b * CIN + lane) * L_;
  bf16* arow = A + (size_t)wv * P_ + lane * 9;
  float s2 = 0.f;
  #pragma unroll
  for (int di = 0; di < 3; ++di){
    const int iy = h + di - 1;
    const bool oky = (unsigned)iy < (unsigned)HW;
    #pragma unroll
    for (int dj = 0; dj < 3; ++dj){
      const int ix = w + dj - 1;
      float v = 0.f;
      if (oky && (unsigned)ix < (unsigned)HW) v = xb[iy * HW + ix];
      s2 += v * v;
      arow[di*3 + dj] = __float2bfloat16(v);
    }
  }
  #pragma unroll
  for (int off = 32; off >= 1; off >>= 1) s2 += __shfl_xor(s2, off);
  if (lane == 0) a2v[wv] = s2;
}

// ---- K2: G = A*C^T, fused dist+softmax -> S (bf16) -------------------------
// tile: 64 n x 256 m, K=576 in chunks of 16. thread-tile 8n x 8m.
__global__ __launch_bounds__(256) void k2_assign(const bf16* __restrict__ A,
                                                 const float* __restrict__ C,
                                                 const float* __restrict__ a2v,
                                                 const float* __restrict__ b2v,
                                                 const float* __restrict__ temp_p,
                                                 bf16* __restrict__ S){
  __shared__ float Al[16][68];    // [k][n], padded
  __shared__ float Cl[16][260];   // [k][m], padded
  const int t  = threadIdx.x;
  const int n0 = blockIdx.x * 64;
  const int tn = t >> 5;          // 0..7  -> n = n0 + tn*8 + i
  const int tm = t & 31;          // 0..31 -> m = tm + 32*j
  float acc[8][8];
  #pragma unroll
  for (int i = 0; i < 8; ++i)
    #pragma unroll
    for (int j = 0; j < 8; ++j) acc[i][j] = 0.f;

  const unsigned short* Au = (const unsigned short*)A;
  const int nnA = t >> 2;
  const int kA  = (t & 3) << 2;

  for (int k0 = 0; k0 < P_; k0 += 16){
    __syncthreads();
    { // stage A tile (transpose), one ushort4 per thread
      ushort4 av4 = *(const ushort4*)(Au + (size_t)(n0 + nnA) * P_ + k0 + kA);
      Al[kA+0][nnA] = bits2f(av4.x);
      Al[kA+1][nnA] = bits2f(av4.y);
      Al[kA+2][nnA] = bits2f(av4.z);
      Al[kA+3][nnA] = bits2f(av4.w);
    }
    #pragma unroll
    for (int e = 0; e < 4; ++e){ // stage C tile (transpose)
      const int idx = t + e * 256;       // 0..1023
      const int mm  = idx >> 2;          // 0..255
      const int kc  = (idx & 3) << 2;
      float4 cv = *(const float4*)(C + (size_t)mm * P_ + k0 + kc);
      Cl[kc+0][mm] = cv.x; Cl[kc+1][mm] = cv.y; Cl[kc+2][mm] = cv.z; Cl[kc+3][mm] = cv.w;
    }
    __syncthreads();
    #pragma unroll
    for (int kk = 0; kk < 16; ++kk){
      float4 a0 = *(const float4*)&Al[kk][tn*8];
      float4 a1 = *(const float4*)&Al[kk][tn*8 + 4];
      float av[8] = {a0.x, a0.y, a0.z, a0.w, a1.x, a1.y, a1.z, a1.w};
      #pragma unroll
      for (int j = 0; j < 8; ++j){
        const float cv = Cl[kk][tm + 32*j];
        #pragma unroll
        for (int i = 0; i < 8; ++i) acc[i][j] = fmaf(av[i], cv, acc[i][j]);
      }
    }
  }

  // epilogue: d = sqrt(a2+b2-2g), softmax over m (32 lanes x 8 vals)
  const float temp = *temp_p;
  float b2r[8];
  #pragma unroll
  for (int j = 0; j < 8; ++j) b2r[j] = b2v[tm + 32*j];
  #pragma unroll
  for (int i = 0; i < 8; ++i){
    const int n = n0 + tn*8 + i;
    const float a2 = a2v[n];
    float lg[8];
    float mx = -3.4e38f;
    #pragma unroll
    for (int j = 0; j < 8; ++j){
      float d2 = fmaxf(a2 + b2r[j] - 2.f * acc[i][j], 1e-12f);
      lg[j] = -temp * sqrtf(d2);
      mx = fmaxf(mx, lg[j]);
    }
    #pragma unroll
    for (int off = 16; off >= 1; off >>= 1) mx = fmaxf(mx, __shfl_xor(mx, off));
    float pe[8]; float sum = 0.f;
    #pragma unroll
    for (int j = 0; j < 8; ++j){ pe[j] = __expf(lg[j] - mx); sum += pe[j]; }
    #pragma unroll
    for (int off = 16; off >= 1; off >>= 1) sum += __shfl_xor(sum, off);
    const float inv = 1.f / sum;
    #pragma unroll
    for (int j = 0; j < 8; ++j)
      S[(size_t)n * M_ + tm + 32*j] = __float2bfloat16(pe[j] * inv);
  }
}

// ---- K3: T = S*C, skip+mask -> F (bf16, in place over A) -------------------
// tile: 128 n x 64 p, K=256 in chunks of 16. thread-tile 8n x 4p.
__global__ __launch_bounds__(256) void k3_transform(const bf16* __restrict__ S,
                                                    const float* __restrict__ C,
                                                    const float* __restrict__ temp_p,
                                                    bf16* __restrict__ AF){
  __shared__ float Sl[16][132];   // [k(m)][n]
  __shared__ float Cl2[16][68];   // [k(m)][p]
  const int t  = threadIdx.x;
  const int n0 = (blockIdx.x / 9) * 128;
  const int p0 = (blockIdx.x % 9) * 64;
  const int tn = t & 15;          // n = n0 + tn + 16*i
  const int tp = t >> 4;          // p = p0 + tp*4 + j
  float acc[8][4];
  #pragma unroll
  for (int i = 0; i < 8; ++i)
    #pragma unroll
    for (int j = 0; j < 4; ++j) acc[i][j] = 0.f;

  const unsigned short* Su = (const unsigned short*)S;

  for (int k0 = 0; k0 < M_; k0 += 16){
    __syncthreads();
    #pragma unroll
    for (int e = 0; e < 2; ++e){ // stage S (transpose): 128 x 16 bf16
      const int idx = t + e * 256;       // 0..511
      const int nn  = idx >> 2;          // 0..127
      const int kS  = (idx & 3) << 2;
      ushort4 sv = *(const ushort4*)(Su + (size_t)(n0 + nn) * M_ + k0 + kS);
      Sl[kS+0][nn] = bits2f(sv.x);
      Sl[kS+1][nn] = bits2f(sv.y);
      Sl[kS+2][nn] = bits2f(sv.z);
      Sl[kS+3][nn] = bits2f(sv.w);
    }
    { // stage C rows (k-major already): 16 x 64 floats
      const int kk = t >> 4;             // 0..15
      const int pc = (t & 15) << 2;      // 0..60
      float4 cv = *(const float4*)(C + (size_t)(k0 + kk) * P_ + p0 + pc);
      *(float4*)&Cl2[kk][pc] = cv;
    }
    __syncthreads();
    #pragma unroll
    for (int kk = 0; kk < 16; ++kk){
      float sv[8];
      #pragma unroll
      for (int i = 0; i < 8; ++i) sv[i] = Sl[kk][tn + 16*i];
      float4 c4 = *(const float4*)&Cl2[kk][tp*4];
      float pv[4] = {c4.x, c4.y, c4.z, c4.w};
      #pragma unroll
      for (int i = 0; i < 8; ++i)
        #pragma unroll
        for (int j = 0; j < 4; ++j) acc[i][j] = fmaf(sv[i], pv[j], acc[i][j]);
    }
  }

  const float temp = *temp_p;
  const float inv  = 1.f / (temp + 1.f);
  #pragma unroll
  for (int i = 0; i < 8; ++i){
    const int n = n0 + tn + 16*i;
    const int l = n % L_;
    #pragma unroll
    for (int j = 0; j < 4; ++j){
      const int p = p0 + tp*4 + j;
      const int o = l * P_ + p;           // within-batch flat offset
      const int q = o / L_;
      const int s = o % L_;
      const int ky = (q / 3) % 3, kx = q % 3;
      const int oy = s / HW,      ox = s % HW;
      const float a = bits2f(((const unsigned short*)AF)[(size_t)n * P_ + p]);
      float f = (temp * acc[i][j] + a) * inv;
      if ((oy == 0 && ky == 0) || (ox == 0 && kx == 0)) f = 0.f;
      AF[(size_t)n * P_ + p] = __float2bfloat16(f);
    }
  }
}

// ---- K4: out[b,co,s] = bias[co] + sum_q W[co,q] * P[b,q,s] -----------------
// tile: 128 co x 64 s, K=576 in chunks of 16. thread-tile 8co x 4s.
__global__ __launch_bounds__(256) void k4_conv(const bf16* __restrict__ F,
                                               const float* __restrict__ W,
                                               const float* __restrict__ bias,
                                               float* __restrict__ out){
  __shared__ float Wl[16][132];   // [k(q)][co]
  __shared__ float Pl[16][68];    // [k(q)][s]
  const int t  = threadIdx.x;
  const int b  = blockIdx.x / 49;
  const int s0 = (blockIdx.x % 49) * 64;
  const int tc = t & 15;          // co = tc + 16*i
  const int ts = t >> 4;          // s  = s0 + ts*4 + j
  float acc[8][4];
  #pragma unroll
  for (int i = 0; i < 8; ++i)
    #pragma unroll
    for (int j = 0; j < 4; ++j) acc[i][j] = 0.f;

  const unsigned short* Fu = (const unsigned short*)F + (size_t)b * ((size_t)P_ * L_);

  for (int q0 = 0; q0 < P_; q0 += 16){
    __syncthreads();
    #pragma unroll
    for (int e = 0; e < 2; ++e){ // stage W (transpose): 128 x 16 floats
      const int idx = t + e * 256;       // 0..511
      const int co  = idx >> 2;          // 0..127
      const int kc  = (idx & 3) << 2;
      float4 wv = *(const float4*)(W + (size_t)co * P_ + q0 + kc);
      Wl[kc+0][co] = wv.x; Wl[kc+1][co] = wv.y; Wl[kc+2][co] = wv.z; Wl[kc+3][co] = wv.w;
    }
    { // stage P rows: 16 x 64 bf16
      const int kk = t >> 4;             // 0..15
      const int sc = (t & 15) << 2;      // 0..60
      ushort4 pv = *(const ushort4*)(Fu + (size_t)(q0 + kk) * L_ + s0 + sc);
      Pl[kk][sc+0] = bits2f(pv.x);
      Pl[kk][sc+1] = bits2f(pv.y);
      Pl[kk][sc+2] = bits2f(pv.z);
      Pl[kk][sc+3] = bits2f(pv.w);
    }
    __syncthreads();
    #pragma unroll
    for (int kk = 0; kk < 16; ++kk){
      float wv[8];
      #pragma unroll
      for (int i = 0; i < 8; ++i) wv[i] = Wl[kk][tc + 16*i];
      float4 p4 = *(const float4*)&Pl[kk][ts*4];
      float pv[4] = {p4.x, p4.y, p4.z, p4.w};
      #pragma unroll
      for (int i = 0; i < 8; ++i)
        #pragma unroll
        for (int j = 0; j < 4; ++j) acc[i][j] = fmaf(wv[i], pv[j], acc[i][j]);
    }
  }

  #pragma unroll
  for (int i = 0; i < 8; ++i){
    const int co = tc + 16*i;
    const float bv = bias[co];
    float* orow = out + ((size_t)b * COUT + co) * L_ + s0 + ts*4;
    #pragma unroll
    for (int j = 0; j < 4; ++j) orow[j] = bv + acc[i][j];
  }
}

extern "C" void kernel_launch(void* const* d_in, const int* in_sizes, int n_in,
                              void* d_out, int out_size, void* d_ws, size_t ws_size,
                              hipStream_t stream){
  const float* x      = (const float*)d_in[0];
  const float* weight = (const float*)d_in[1];
  const float* bias   = (const float*)d_in[2];
  const float* cc     = (const float*)d_in[3];
  const float* temp_p = (const float*)d_in[4];
  float* out = (float*)d_out;

  char* ws = (char*)d_ws;
  const size_t off_A  = 0;                          // N*P bf16 = 115,605,504 B
  const size_t off_S  = 115605504;                  // N*M bf16 =  51,380,224 B
  const size_t off_a2 = off_S + 51380224;           // N f32    =     401,408 B
  const size_t off_b2 = off_a2 + 401408;            // 256 f32
  bf16*  A   = (bf16*)(ws + off_A);
  bf16*  S   = (bf16*)(ws + off_S);
  float* a2v = (float*)(ws + off_a2);
  float* b2v = (float*)(ws + off_b2);

  k0_b2     <<<1,          256, 0, stream>>>(cc, b2v);
  k1_unfold <<<N_/4,       256, 0, stream>>>(x, A, a2v);
  k2_assign <<<N_/64,      256, 0, stream>>>(A, cc, a2v, b2v, temp_p, S);
  k3_transform<<<(N_/128)*9,256, 0, stream>>>(S, cc, temp_p, A);
  k4_conv   <<<B_*49,      256, 0, stream>>>(A, weight, bias, out);
}

// Round 2
// 418.589 us; speedup vs baseline: 2.9001x; 2.9001x over previous
//
#include <hip/hip_runtime.h>
#include <hip/hip_bf16.h>

#define B_    32
#define CIN   64
#define HW    56
#define COUT  128
#define M_    256
#define P_    576
#define L_    3136
#define N_    100352

typedef __hip_bfloat16 bf16;
typedef unsigned short u16;
typedef __attribute__((ext_vector_type(8))) short bf16x8;
typedef __attribute__((ext_vector_type(8))) unsigned short u16x8;
typedef __attribute__((ext_vector_type(4))) float f32x4;

__device__ __forceinline__ float bits2f(u16 u){ return __uint_as_float(((unsigned)u) << 16); }
__device__ __forceinline__ u16 f2bf(float f){
  bf16 h = __float2bfloat16(f);
  return *(u16*)&h;
}
__device__ __forceinline__ void gload16(const void* g, void* l){
  __builtin_amdgcn_global_load_lds((const __attribute__((address_space(1))) void*)g,
                                   (__attribute__((address_space(3))) void*)l, 16, 0, 0);
}

// ---- K0: C -> Cb (bf16 [m][p]), Ct (bf16 [p][m]), b2; W -> Wb (bf16) -------
__global__ __launch_bounds__(256) void k0_prep(const float* __restrict__ C,
                                               const float* __restrict__ W,
                                               u16* __restrict__ Cb, u16* __restrict__ Ct,
                                               float* __restrict__ b2v, u16* __restrict__ Wb){
  __shared__ float red[4];
  const int t = threadIdx.x;
  const int bid = blockIdx.x;
  if (bid < M_){
    const int m = bid;
    float s = 0.f;
    for (int p = t; p < P_; p += 256){
      u16 h = f2bf(C[(size_t)m*P_ + p]);
      float vr = bits2f(h);
      s += vr*vr;
      Cb[(size_t)m*P_ + p] = h;
      Ct[(size_t)p*M_ + m] = h;
    }
    #pragma unroll
    for (int off = 32; off >= 1; off >>= 1) s += __shfl_xor(s, off);
    if ((t & 63) == 0) red[t >> 6] = s;
    __syncthreads();
    if (t == 0) b2v[m] = red[0] + red[1] + red[2] + red[3];
  } else {
    const int co = bid - M_;
    for (int q = t; q < P_; q += 256)
      Wb[(size_t)co*P_ + q] = f2bf(W[(size_t)co*P_ + q]);
  }
}

// ---- K1: unfold -> A (bf16 [n][p]) + a2[n] (from rounded values) -----------
__global__ __launch_bounds__(256) void k1_unfold(const float* __restrict__ x,
                                                 u16* __restrict__ A,
                                                 float* __restrict__ a2v){
  const int wv   = blockIdx.x * 4 + (threadIdx.x >> 6);
  const int lane = threadIdx.x & 63;              // lane = input channel
  const int b = wv / L_, l = wv % L_;
  const int h = l / HW, w = l % HW;
  const float* xb = x + ((size_t)b * CIN + lane) * L_;
  u16* arow = A + (size_t)wv * P_ + lane * 9;
  float s2 = 0.f;
  #pragma unroll
  for (int di = 0; di < 3; ++di){
    const int iy = h + di - 1;
    const bool oky = (unsigned)iy < (unsigned)HW;
    #pragma unroll
    for (int dj = 0; dj < 3; ++dj){
      const int ix = w + dj - 1;
      float v = 0.f;
      if (oky && (unsigned)ix < (unsigned)HW) v = xb[iy * HW + ix];
      u16 hh = f2bf(v);
      float vr = bits2f(hh);
      s2 += vr * vr;
      arow[di*3 + dj] = hh;
    }
  }
  #pragma unroll
  for (int off = 32; off >= 1; off >>= 1) s2 += __shfl_xor(s2, off);
  if (lane == 0) a2v[wv] = s2;
}

// ---- K2: MFMA GEMM G=A*Cb^T (64n x 256m tile), fused dist+softmax -> S -----
__global__ __launch_bounds__(256) void k2_assign(const u16* __restrict__ A,
    const u16* __restrict__ Cb, const float* __restrict__ a2v,
    const float* __restrict__ b2v, const float* __restrict__ temp_p,
    u16* __restrict__ S){
  __shared__ short Al[64*32];     // 4 KB
  __shared__ short Cl[256*32];    // 16 KB
  const int t = threadIdx.x;
  const int lane = t & 63;
  const int wm = t >> 6;          // wave -> m quadrant
  const int g  = lane >> 4;
  const int lr = lane & 15;
  const int n0 = blockIdx.x * 64;
  const int sw = (g ^ (lr & 3)) << 3;   // swizzled k-chunk (shorts)

  f32x4 acc[4][4];
  #pragma unroll
  for (int i = 0; i < 4; ++i)
    #pragma unroll
    for (int j = 0; j < 4; ++j) acc[i][j] = (f32x4){0.f,0.f,0.f,0.f};

  const int arow = t >> 2, ach = t & 3;
  const int agch = ach ^ (arow & 3);

  for (int k0 = 0; k0 < P_; k0 += 32){
    __syncthreads();
    gload16(A + (size_t)(n0 + arow)*P_ + k0 + agch*8, &Al[t*8]);
    #pragma unroll
    for (int e = 0; e < 4; ++e){
      const int c = t + e*256;
      const int mr = c >> 2, ch = c & 3;
      gload16(Cb + (size_t)mr*P_ + k0 + (ch ^ (mr & 3))*8, &Cl[c*8]);
    }
    __syncthreads();
    bf16x8 af[4], bb[4];
    #pragma unroll
    for (int i = 0; i < 4; ++i)
      af[i] = *(const bf16x8*)&Al[(i*16 + lr)*32 + sw];
    #pragma unroll
    for (int j = 0; j < 4; ++j)
      bb[j] = *(const bf16x8*)&Cl[(wm*64 + j*16 + lr)*32 + sw];
    #pragma unroll
    for (int i = 0; i < 4; ++i)
      #pragma unroll
      for (int j = 0; j < 4; ++j)
        acc[i][j] = __builtin_amdgcn_mfma_f32_16x16x32_bf16(af[i], bb[j], acc[i][j], 0, 0, 0);
  }

  // epilogue: d = sqrt(a2+b2-2g) -> softmax over all 256 m
  const float temp = *temp_p;
  float a2r[4][4], b2r[4];
  #pragma unroll
  for (int i = 0; i < 4; ++i)
    #pragma unroll
    for (int r = 0; r < 4; ++r) a2r[i][r] = a2v[n0 + i*16 + g*4 + r];
  #pragma unroll
  for (int j = 0; j < 4; ++j) b2r[j] = b2v[wm*64 + j*16 + lr];

  float rmax[4][4];
  #pragma unroll
  for (int i = 0; i < 4; ++i)
    #pragma unroll
    for (int r = 0; r < 4; ++r) rmax[i][r] = -3.4e38f;

  #pragma unroll
  for (int i = 0; i < 4; ++i)
    #pragma unroll
    for (int j = 0; j < 4; ++j)
      #pragma unroll
      for (int r = 0; r < 4; ++r){
        float d2 = fmaxf(a2r[i][r] + b2r[j] - 2.f*acc[i][j][r], 1e-12f);
        float lg = -temp * sqrtf(d2);
        acc[i][j][r] = lg;
        rmax[i][r] = fmaxf(rmax[i][r], lg);
      }
  #pragma unroll
  for (int i = 0; i < 4; ++i)
    #pragma unroll
    for (int r = 0; r < 4; ++r){
      float v = rmax[i][r];
      v = fmaxf(v, __shfl_xor(v, 1));
      v = fmaxf(v, __shfl_xor(v, 2));
      v = fmaxf(v, __shfl_xor(v, 4));
      v = fmaxf(v, __shfl_xor(v, 8));
      rmax[i][r] = v;
    }
  float* red = (float*)Al;
  __syncthreads();
  if (lr == 0){
    #pragma unroll
    for (int i = 0; i < 4; ++i)
      #pragma unroll
      for (int r = 0; r < 4; ++r) red[wm*64 + i*16 + g*4 + r] = rmax[i][r];
  }
  __syncthreads();
  #pragma unroll
  for (int i = 0; i < 4; ++i)
    #pragma unroll
    for (int r = 0; r < 4; ++r){
      const int row = i*16 + g*4 + r;
      rmax[i][r] = fmaxf(fmaxf(red[row], red[64+row]), fmaxf(red[128+row], red[192+row]));
    }
  float rsum[4][4];
  #pragma unroll
  for (int i = 0; i < 4; ++i)
    #pragma unroll
    for (int r = 0; r < 4; ++r) rsum[i][r] = 0.f;
  #pragma unroll
  for (int i = 0; i < 4; ++i)
    #pragma unroll
    for (int j = 0; j < 4; ++j)
      #pragma unroll
      for (int r = 0; r < 4; ++r){
        float pe = __expf(acc[i][j][r] - rmax[i][r]);
        acc[i][j][r] = pe;
        rsum[i][r] += pe;
      }
  #pragma unroll
  for (int i = 0; i < 4; ++i)
    #pragma unroll
    for (int r = 0; r < 4; ++r){
      float v = rsum[i][r];
      v += __shfl_xor(v, 1);
      v += __shfl_xor(v, 2);
      v += __shfl_xor(v, 4);
      v += __shfl_xor(v, 8);
      rsum[i][r] = v;
    }
  __syncthreads();
  if (lr == 0){
    #pragma unroll
    for (int i = 0; i < 4; ++i)
      #pragma unroll
      for (int r = 0; r < 4; ++r) red[wm*64 + i*16 + g*4 + r] = rsum[i][r];
  }
  __syncthreads();
  #pragma unroll
  for (int i = 0; i < 4; ++i)
    #pragma unroll
    for (int r = 0; r < 4; ++r){
      const int row = i*16 + g*4 + r;
      const float inv = 1.f / (red[row] + red[64+row] + red[128+row] + red[192+row]);
      #pragma unroll
      for (int j = 0; j < 4; ++j)
        S[(size_t)(n0 + row)*M_ + wm*64 + j*16 + lr] = f2bf(acc[i][j][r] * inv);
    }
}

// ---- K3: MFMA GEMM T=S*C (128n x 192p tile), skip -> AF in place -----------
__global__ __launch_bounds__(384) void k3_transform(const u16* __restrict__ S,
    const u16* __restrict__ Ct, const float* __restrict__ temp_p,
    u16* __restrict__ AF){
  __shared__ short Sl[128*32];    // 8 KB
  __shared__ short Ctl[192*32];   // 12 KB
  const int t = threadIdx.x;
  const int lane = t & 63;
  const int w = t >> 6;           // 0..5
  const int wn = w / 3;           // 0..1
  const int wp = w - wn*3;        // 0..2
  const int g  = lane >> 4;
  const int lr = lane & 15;
  const int n0 = blockIdx.x * 128;
  const int p0 = blockIdx.y * 192;
  const int sw = (g ^ (lr & 3)) << 3;

  f32x4 acc[4][4];
  #pragma unroll
  for (int i = 0; i < 4; ++i)
    #pragma unroll
    for (int j = 0; j < 4; ++j) acc[i][j] = (f32x4){0.f,0.f,0.f,0.f};

  for (int k0 = 0; k0 < M_; k0 += 32){
    __syncthreads();
    { const int c = t;           const int r = c >> 2, ch = c & 3;
      gload16(S + (size_t)(n0 + r)*M_ + k0 + (ch ^ (r & 3))*8, &Sl[c*8]); }
    if (t < 128){
      const int c = t + 384;     const int r = c >> 2, ch = c & 3;
      gload16(S + (size_t)(n0 + r)*M_ + k0 + (ch ^ (r & 3))*8, &Sl[c*8]); }
    #pragma unroll
    for (int e = 0; e < 2; ++e){
      const int c = t + e*384;
      const int r = c >> 2, ch = c & 3;
      gload16(Ct + (size_t)(p0 + r)*M_ + k0 + (ch ^ (r & 3))*8, &Ctl[c*8]);
    }
    __syncthreads();
    bf16x8 af[4], bb[4];
    #pragma unroll
    for (int i = 0; i < 4; ++i)
      af[i] = *(const bf16x8*)&Sl[(wn*64 + i*16 + lr)*32 + sw];
    #pragma unroll
    for (int j = 0; j < 4; ++j)
      bb[j] = *(const bf16x8*)&Ctl[(wp*64 + j*16 + lr)*32 + sw];
    #pragma unroll
    for (int i = 0; i < 4; ++i)
      #pragma unroll
      for (int j = 0; j < 4; ++j)
        acc[i][j] = __builtin_amdgcn_mfma_f32_16x16x32_bf16(af[i], bb[j], acc[i][j], 0, 0, 0);
  }

  const float temp = *temp_p;
  const float inv = 1.f / (temp + 1.f);
  #pragma unroll
  for (int i = 0; i < 4; ++i)
    #pragma unroll
    for (int r = 0; r < 4; ++r){
      const int n = n0 + wn*64 + i*16 + g*4 + r;
      #pragma unroll
      for (int j = 0; j < 4; ++j){
        const int p = p0 + wp*64 + j*16 + lr;
        const size_t idx = (size_t)n*P_ + p;
        float a = bits2f(AF[idx]);
        AF[idx] = f2bf((temp*acc[i][j][r] + a)*inv);
      }
    }
}

// ---- K4: MFMA GEMM out = Wb * F (+bias), mask fused into F staging ---------
// F viewed as [b][q][s] flat; B-tile transposed to [s][q] in LDS (stride 40).
__global__ __launch_bounds__(256) void k4_conv(const u16* __restrict__ F,
    const u16* __restrict__ Wb, const float* __restrict__ bias,
    float* __restrict__ out){
  __shared__ short Wl[128*32];    // 8 KB
  __shared__ short Fl[128*40];    // 10 KB, row stride 40 shorts (16B aligned)
  const int t = threadIdx.x;
  const int lane = t & 63;
  const int w = t >> 6;           // 0..3
  const int wn = w >> 1;          // co half
  const int ws = w & 1;           // s half
  const int g  = lane >> 4;
  const int lr = lane & 15;
  const int b  = blockIdx.y;
  const int s0 = blockIdx.x * 128;
  const int sw = (g ^ (lr & 3)) << 3;
  const u16* Fb = F + (size_t)b * ((size_t)P_ * L_);

  f32x4 acc[4][4];
  #pragma unroll
  for (int i = 0; i < 4; ++i)
    #pragma unroll
    for (int j = 0; j < 4; ++j) acc[i][j] = (f32x4){0.f,0.f,0.f,0.f};

  for (int q0 = 0; q0 < P_; q0 += 32){
    __syncthreads();
    #pragma unroll
    for (int e = 0; e < 2; ++e){
      const int c = t + e*256;
      const int r = c >> 2, ch = c & 3;
      gload16(Wb + (size_t)r*P_ + q0 + (ch ^ (r & 3))*8, &Wl[c*8]);
    }
    #pragma unroll
    for (int e = 0; e < 2; ++e){
      const int c = t + e*256;
      const int ql = c & 31, sch = c >> 5;
      const int q  = q0 + ql;
      const int sbase = s0 + sch*8;
      const int scl = (sbase < L_ - 8) ? sbase : (L_ - 8);
      u16x8 v = *(const u16x8*)(Fb + (size_t)q*L_ + scl);
      const int q3 = q/3;
      const bool kx0 = (q - q3*3) == 0;
      const bool ky0 = (q3 % 3) == 0;
      const int r0 = sbase % 56;
      #pragma unroll
      for (int u = 0; u < 8; ++u){
        const bool m0 = ky0 && (sbase + u) < 56;
        const bool m1 = kx0 && ((r0 + u) == 0 || (r0 + u) == 56);
        Fl[(sch*8 + u)*40 + ql] = (m0 || m1) ? (short)0 : (short)v[u];
      }
    }
    __syncthreads();
    bf16x8 af[4], bb[4];
    #pragma unroll
    for (int i = 0; i < 4; ++i)
      af[i] = *(const bf16x8*)&Wl[(wn*64 + i*16 + lr)*32 + sw];
    #pragma unroll
    for (int j = 0; j < 4; ++j)
      bb[j] = *(const bf16x8*)&Fl[(ws*64 + j*16 + lr)*40 + g*8];
    #pragma unroll
    for (int i = 0; i < 4; ++i)
      #pragma unroll
      for (int j = 0; j < 4; ++j)
        acc[i][j] = __builtin_amdgcn_mfma_f32_16x16x32_bf16(af[i], bb[j], acc[i][j], 0, 0, 0);
  }

  #pragma unroll
  for (int i = 0; i < 4; ++i)
    #pragma unroll
    for (int r = 0; r < 4; ++r){
      const int co = wn*64 + i*16 + g*4 + r;
      const float bv = bias[co];
      #pragma unroll
      for (int j = 0; j < 4; ++j){
        const int s = s0 + ws*64 + j*16 + lr;
        if (s < L_) out[((size_t)b*COUT + co)*L_ + s] = acc[i][j][r] + bv;
      }
    }
}

extern "C" void kernel_launch(void* const* d_in, const int* in_sizes, int n_in,
                              void* d_out, int out_size, void* d_ws, size_t ws_size,
                              hipStream_t stream){
  const float* x      = (const float*)d_in[0];
  const float* weight = (const float*)d_in[1];
  const float* bias   = (const float*)d_in[2];
  const float* cc     = (const float*)d_in[3];
  const float* temp_p = (const float*)d_in[4];
  float* out = (float*)d_out;

  char* ws = (char*)d_ws;
  u16*   A   = (u16*)(ws);                 // N*P bf16   = 115,605,504 B
  u16*   S   = (u16*)(ws + 115605504);     // N*M bf16   =  51,380,224 B
  float* a2v = (float*)(ws + 166985728);   // N f32      =     401,408 B
  float* b2v = (float*)(ws + 167387136);   // 256 f32    =       1,024 B
  u16*   Cb  = (u16*)(ws + 167388160);     // 256x576 bf16 =   294,912 B
  u16*   Ct  = (u16*)(ws + 167683072);     // 576x256 bf16 =   294,912 B
  u16*   Wb  = (u16*)(ws + 167977984);     // 128x576 bf16 =   147,456 B

  k0_prep   <<<384,               256, 0, stream>>>(cc, weight, Cb, Ct, b2v, Wb);
  k1_unfold <<<N_/4,              256, 0, stream>>>(x, A, a2v);
  k2_assign <<<N_/64,             256, 0, stream>>>(A, Cb, a2v, b2v, temp_p, S);
  k3_transform<<<dim3(N_/128, 3), 384, 0, stream>>>(S, Ct, temp_p, A);
  k4_conv   <<<dim3(25, B_),      256, 0, stream>>>(A, Wb, bias, out);
}

// Round 3
// 399.159 us; speedup vs baseline: 3.0412x; 1.0487x over previous
//
#include <hip/hip_runtime.h>
#include <hip/hip_bf16.h>

#define B_    32
#define CIN   64
#define HW    56
#define COUT  128
#define M_    256
#define P_    576
#define L_    3136
#define N_    100352

typedef __hip_bfloat16 bf16;
typedef unsigned short u16;
typedef __attribute__((ext_vector_type(8))) short bf16x8;
typedef __attribute__((ext_vector_type(8))) unsigned short u16x8;
typedef __attribute__((ext_vector_type(4))) float f32x4;

__device__ __forceinline__ float bits2f(u16 u){ return __uint_as_float(((unsigned)u) << 16); }
__device__ __forceinline__ u16 f2bf(float f){
  bf16 h = __float2bfloat16(f);
  return *(u16*)&h;
}
__device__ __forceinline__ void gload16(const void* g, void* l){
  __builtin_amdgcn_global_load_lds((const __attribute__((address_space(1))) void*)g,
                                   (__attribute__((address_space(3))) void*)l, 16, 0, 0);
}

// ---- K0: C -> Cb (bf16 [m][p]), Ct (bf16 [p][m]), b2; W -> Wb (bf16) -------
__global__ __launch_bounds__(256) void k0_prep(const float* __restrict__ C,
                                               const float* __restrict__ W,
                                               u16* __restrict__ Cb, u16* __restrict__ Ct,
                                               float* __restrict__ b2v, u16* __restrict__ Wb){
  __shared__ float red[4];
  const int t = threadIdx.x;
  const int bid = blockIdx.x;
  if (bid < M_){
    const int m = bid;
    float s = 0.f;
    for (int p = t; p < P_; p += 256){
      u16 h = f2bf(C[(size_t)m*P_ + p]);
      float vr = bits2f(h);
      s += vr*vr;
      Cb[(size_t)m*P_ + p] = h;
      Ct[(size_t)p*M_ + m] = h;
    }
    #pragma unroll
    for (int off = 32; off >= 1; off >>= 1) s += __shfl_xor(s, off);
    if ((t & 63) == 0) red[t >> 6] = s;
    __syncthreads();
    if (t == 0) b2v[m] = red[0] + red[1] + red[2] + red[3];
  } else {
    const int co = bid - M_;
    for (int q = t; q < P_; q += 256)
      Wb[(size_t)co*P_ + q] = f2bf(W[(size_t)co*P_ + q]);
  }
}

// ---- K1: unfold -> A (bf16 [n][p]) + a2[n]; LDS-staged coalesced stores ----
__global__ __launch_bounds__(256) void k1_unfold(const float* __restrict__ x,
                                                 u16* __restrict__ A,
                                                 float* __restrict__ a2v){
  __shared__ __align__(16) u16 st[4][P_];       // 4 x 1152 B
  const int wid  = threadIdx.x >> 6;
  const int lane = threadIdx.x & 63;            // lane = input channel
  const int wv = blockIdx.x * 4 + wid;          // patch index n
  const int b = wv / L_, l = wv % L_;
  const int h = l / HW, w = l % HW;
  const float* xb = x + ((size_t)b * CIN + lane) * L_;
  float s2 = 0.f;
  #pragma unroll
  for (int di = 0; di < 3; ++di){
    const int iy = h + di - 1;
    const bool oky = (unsigned)iy < (unsigned)HW;
    #pragma unroll
    for (int dj = 0; dj < 3; ++dj){
      const int ix = w + dj - 1;
      float v = 0.f;
      if (oky && (unsigned)ix < (unsigned)HW) v = xb[iy * HW + ix];
      u16 hh = f2bf(v);
      float vr = bits2f(hh);
      s2 += vr * vr;
      st[wid][lane*9 + di*3 + dj] = hh;
    }
  }
  #pragma unroll
  for (int off = 32; off >= 1; off >>= 1) s2 += __shfl_xor(s2, off);
  if (lane == 0) a2v[wv] = s2;
  // coalesced row store: 72 u16x8 = 1152 B contiguous
  u16* arow = A + (size_t)wv * P_;
  const u16x8* src = (const u16x8*)st[wid];
  *(u16x8*)(arow + lane*8) = src[lane];
  if (lane < 8) *(u16x8*)(arow + 512 + lane*8) = src[64 + lane];
}

// ---- K2: MFMA GEMM G=A*Cb^T (64n x 256m), fused dist+softmax -> S ----------
__global__ __launch_bounds__(256) void k2_assign(const u16* __restrict__ A,
    const u16* __restrict__ Cb, const float* __restrict__ a2v,
    const float* __restrict__ b2v, const float* __restrict__ temp_p,
    u16* __restrict__ S){
  __shared__ __align__(16) char lds2[64*264*2]; // 33792 B union
  short* Al = (short*)lds2;                     // 64*32  shorts (4 KB)
  short* Cl = (short*)(lds2 + 4096);            // 256*32 shorts (16 KB)
  float* red = (float*)lds2;                    // 256 floats (epilogue)
  u16*   Sl  = (u16*)lds2;                      // 64 x 264 (store staging)
  const int t = threadIdx.x;
  const int lane = t & 63;
  const int wm = t >> 6;
  const int g  = lane >> 4;
  const int lr = lane & 15;
  const int n0 = blockIdx.x * 64;
  const int sw = (g ^ (lr & 3)) << 3;

  f32x4 acc[4][4];
  #pragma unroll
  for (int i = 0; i < 4; ++i)
    #pragma unroll
    for (int j = 0; j < 4; ++j) acc[i][j] = (f32x4){0.f,0.f,0.f,0.f};

  const int arow = t >> 2, ach = t & 3;
  const int agch = ach ^ (arow & 3);

  for (int k0 = 0; k0 < P_; k0 += 32){
    __syncthreads();
    gload16(A + (size_t)(n0 + arow)*P_ + k0 + agch*8, &Al[t*8]);
    #pragma unroll
    for (int e = 0; e < 4; ++e){
      const int c = t + e*256;
      const int mr = c >> 2, ch = c & 3;
      gload16(Cb + (size_t)mr*P_ + k0 + (ch ^ (mr & 3))*8, &Cl[c*8]);
    }
    __syncthreads();
    bf16x8 af[4], bb[4];
    #pragma unroll
    for (int i = 0; i < 4; ++i)
      af[i] = *(const bf16x8*)&Al[(i*16 + lr)*32 + sw];
    #pragma unroll
    for (int j = 0; j < 4; ++j)
      bb[j] = *(const bf16x8*)&Cl[(wm*64 + j*16 + lr)*32 + sw];
    #pragma unroll
    for (int i = 0; i < 4; ++i)
      #pragma unroll
      for (int j = 0; j < 4; ++j)
        acc[i][j] = __builtin_amdgcn_mfma_f32_16x16x32_bf16(af[i], bb[j], acc[i][j], 0, 0, 0);
  }

  // epilogue: d = sqrt(a2+b2-2g) -> softmax over all 256 m
  const float temp = *temp_p;
  float a2r[4][4], b2r[4];
  #pragma unroll
  for (int i = 0; i < 4; ++i)
    #pragma unroll
    for (int r = 0; r < 4; ++r) a2r[i][r] = a2v[n0 + i*16 + g*4 + r];
  #pragma unroll
  for (int j = 0; j < 4; ++j) b2r[j] = b2v[wm*64 + j*16 + lr];

  float rmax[4][4];
  #pragma unroll
  for (int i = 0; i < 4; ++i)
    #pragma unroll
    for (int r = 0; r < 4; ++r) rmax[i][r] = -3.4e38f;

  #pragma unroll
  for (int i = 0; i < 4; ++i)
    #pragma unroll
    for (int j = 0; j < 4; ++j)
      #pragma unroll
      for (int r = 0; r < 4; ++r){
        float d2 = fmaxf(a2r[i][r] + b2r[j] - 2.f*acc[i][j][r], 1e-12f);
        float lg = -temp * sqrtf(d2);
        acc[i][j][r] = lg;
        rmax[i][r] = fmaxf(rmax[i][r], lg);
      }
  #pragma unroll
  for (int i = 0; i < 4; ++i)
    #pragma unroll
    for (int r = 0; r < 4; ++r){
      float v = rmax[i][r];
      v = fmaxf(v, __shfl_xor(v, 1));
      v = fmaxf(v, __shfl_xor(v, 2));
      v = fmaxf(v, __shfl_xor(v, 4));
      v = fmaxf(v, __shfl_xor(v, 8));
      rmax[i][r] = v;
    }
  __syncthreads();
  if (lr == 0){
    #pragma unroll
    for (int i = 0; i < 4; ++i)
      #pragma unroll
      for (int r = 0; r < 4; ++r) red[wm*64 + i*16 + g*4 + r] = rmax[i][r];
  }
  __syncthreads();
  #pragma unroll
  for (int i = 0; i < 4; ++i)
    #pragma unroll
    for (int r = 0; r < 4; ++r){
      const int row = i*16 + g*4 + r;
      rmax[i][r] = fmaxf(fmaxf(red[row], red[64+row]), fmaxf(red[128+row], red[192+row]));
    }
  float rsum[4][4];
  #pragma unroll
  for (int i = 0; i < 4; ++i)
    #pragma unroll
    for (int r = 0; r < 4; ++r) rsum[i][r] = 0.f;
  #pragma unroll
  for (int i = 0; i < 4; ++i)
    #pragma unroll
    for (int j = 0; j < 4; ++j)
      #pragma unroll
      for (int r = 0; r < 4; ++r){
        float pe = __expf(acc[i][j][r] - rmax[i][r]);
        acc[i][j][r] = pe;
        rsum[i][r] += pe;
      }
  #pragma unroll
  for (int i = 0; i < 4; ++i)
    #pragma unroll
    for (int r = 0; r < 4; ++r){
      float v = rsum[i][r];
      v += __shfl_xor(v, 1);
      v += __shfl_xor(v, 2);
      v += __shfl_xor(v, 4);
      v += __shfl_xor(v, 8);
      rsum[i][r] = v;
    }
  __syncthreads();
  if (lr == 0){
    #pragma unroll
    for (int i = 0; i < 4; ++i)
      #pragma unroll
      for (int r = 0; r < 4; ++r) red[wm*64 + i*16 + g*4 + r] = rsum[i][r];
  }
  __syncthreads();
  float invr[4][4];
  #pragma unroll
  for (int i = 0; i < 4; ++i)
    #pragma unroll
    for (int r = 0; r < 4; ++r){
      const int row = i*16 + g*4 + r;
      invr[i][r] = 1.f / (red[row] + red[64+row] + red[128+row] + red[192+row]);
    }
  __syncthreads();   // red reads done; LDS free for Sl
  #pragma unroll
  for (int i = 0; i < 4; ++i)
    #pragma unroll
    for (int r = 0; r < 4; ++r)
      #pragma unroll
      for (int j = 0; j < 4; ++j)
        Sl[(i*16 + g*4 + r)*264 + wm*64 + j*16 + lr] = f2bf(acc[i][j][r] * invr[i][r]);
  __syncthreads();
  for (int v = t; v < 64*32; v += 256){
    const int row = v >> 5, col = v & 31;
    u16x8 d = *(const u16x8*)&Sl[row*264 + col*8];
    *(u16x8*)(S + (size_t)(n0 + row)*M_ + col*8) = d;
  }
}

// ---- K3: MFMA GEMM T=S*C (128n x 192p), skip fused in coalesced store ------
__global__ __launch_bounds__(384) void k3_transform(const u16* __restrict__ S,
    const u16* __restrict__ Ct, const float* __restrict__ temp_p,
    u16* __restrict__ AF){
  __shared__ __align__(16) char lds3[128*200*2]; // 51200 B union
  short* Sl  = (short*)lds3;                     // 128*32 shorts (8 KB)
  short* Ctl = (short*)(lds3 + 8192);            // 192*32 shorts (12 KB)
  u16*   Fl  = (u16*)lds3;                       // 128 x 200 (store staging)
  const int t = threadIdx.x;
  const int lane = t & 63;
  const int w = t >> 6;           // 0..5
  const int wn = w / 3;           // 0..1
  const int wp = w - wn*3;        // 0..2
  const int g  = lane >> 4;
  const int lr = lane & 15;
  const int n0 = blockIdx.x * 128;
  const int p0 = blockIdx.y * 192;
  const int sw = (g ^ (lr & 3)) << 3;

  f32x4 acc[4][4];
  #pragma unroll
  for (int i = 0; i < 4; ++i)
    #pragma unroll
    for (int j = 0; j < 4; ++j) acc[i][j] = (f32x4){0.f,0.f,0.f,0.f};

  for (int k0 = 0; k0 < M_; k0 += 32){
    __syncthreads();
    { const int c = t;           const int r = c >> 2, ch = c & 3;
      gload16(S + (size_t)(n0 + r)*M_ + k0 + (ch ^ (r & 3))*8, &Sl[c*8]); }
    if (t < 128){
      const int c = t + 384;     const int r = c >> 2, ch = c & 3;
      gload16(S + (size_t)(n0 + r)*M_ + k0 + (ch ^ (r & 3))*8, &Sl[c*8]); }
    #pragma unroll
    for (int e = 0; e < 2; ++e){
      const int c = t + e*384;
      const int r = c >> 2, ch = c & 3;
      gload16(Ct + (size_t)(p0 + r)*M_ + k0 + (ch ^ (r & 3))*8, &Ctl[c*8]);
    }
    __syncthreads();
    bf16x8 af[4], bb[4];
    #pragma unroll
    for (int i = 0; i < 4; ++i)
      af[i] = *(const bf16x8*)&Sl[(wn*64 + i*16 + lr)*32 + sw];
    #pragma unroll
    for (int j = 0; j < 4; ++j)
      bb[j] = *(const bf16x8*)&Ctl[(wp*64 + j*16 + lr)*32 + sw];
    #pragma unroll
    for (int i = 0; i < 4; ++i)
      #pragma unroll
      for (int j = 0; j < 4; ++j)
        acc[i][j] = __builtin_amdgcn_mfma_f32_16x16x32_bf16(af[i], bb[j], acc[i][j], 0, 0, 0);
  }

  const float temp = *temp_p;
  const float inv = 1.f / (temp + 1.f);
  const float tscale = temp * inv;
  __syncthreads();   // staging reads done; LDS free for Fl
  #pragma unroll
  for (int i = 0; i < 4; ++i)
    #pragma unroll
    for (int r = 0; r < 4; ++r)
      #pragma unroll
      for (int j = 0; j < 4; ++j)
        Fl[(wn*64 + i*16 + g*4 + r)*200 + wp*64 + j*16 + lr] = f2bf(acc[i][j][r] * tscale);
  __syncthreads();
  for (int v = t; v < 128*24; v += 384){
    const int row = v / 24, col = v - row*24;
    u16x8 tv = *(const u16x8*)&Fl[row*200 + col*8];
    u16* gp = AF + (size_t)(n0 + row)*P_ + p0 + col*8;
    u16x8 av = *(const u16x8*)gp;
    u16x8 o;
    #pragma unroll
    for (int e = 0; e < 8; ++e)
      o[e] = f2bf(bits2f(tv[e]) + bits2f(av[e]) * inv);
    *(u16x8*)gp = o;
  }
}

// ---- K4: MFMA GEMM out = Wb * F (+bias), mask fused into F staging ---------
__global__ __launch_bounds__(256) void k4_conv(const u16* __restrict__ F,
    const u16* __restrict__ Wb, const float* __restrict__ bias,
    float* __restrict__ out){
  __shared__ short Wl[128*32];    // 8 KB
  __shared__ short Fl[128*40];    // 10 KB, row stride 40 shorts (16B aligned)
  const int t = threadIdx.x;
  const int lane = t & 63;
  const int w = t >> 6;           // 0..3
  const int wn = w >> 1;          // co half
  const int ws = w & 1;           // s half
  const int g  = lane >> 4;
  const int lr = lane & 15;
  const int b  = blockIdx.y;
  const int s0 = blockIdx.x * 128;
  const int sw = (g ^ (lr & 3)) << 3;
  const u16* Fb = F + (size_t)b * ((size_t)P_ * L_);

  f32x4 acc[4][4];
  #pragma unroll
  for (int i = 0; i < 4; ++i)
    #pragma unroll
    for (int j = 0; j < 4; ++j) acc[i][j] = (f32x4){0.f,0.f,0.f,0.f};

  for (int q0 = 0; q0 < P_; q0 += 32){
    __syncthreads();
    #pragma unroll
    for (int e = 0; e < 2; ++e){
      const int c = t + e*256;
      const int r = c >> 2, ch = c & 3;
      gload16(Wb + (size_t)r*P_ + q0 + (ch ^ (r & 3))*8, &Wl[c*8]);
    }
    #pragma unroll
    for (int e = 0; e < 2; ++e){
      const int c = t + e*256;
      const int ql = c & 31, sch = c >> 5;
      const int q  = q0 + ql;
      const int sbase = s0 + sch*8;
      const int scl = (sbase < L_ - 8) ? sbase : (L_ - 8);
      u16x8 v = *(const u16x8*)(Fb + (size_t)q*L_ + scl);
      const int q3 = q/3;
      const bool kx0 = (q - q3*3) == 0;
      const bool ky0 = (q3 % 3) == 0;
      const int r0 = sbase % 56;
      #pragma unroll
      for (int u = 0; u < 8; ++u){
        const bool m0 = ky0 && (sbase + u) < 56;
        const bool m1 = kx0 && ((r0 + u) == 0 || (r0 + u) == 56);
        Fl[(sch*8 + u)*40 + ql] = (m0 || m1) ? (short)0 : (short)v[u];
      }
    }
    __syncthreads();
    bf16x8 af[4], bb[4];
    #pragma unroll
    for (int i = 0; i < 4; ++i)
      af[i] = *(const bf16x8*)&Wl[(wn*64 + i*16 + lr)*32 + sw];
    #pragma unroll
    for (int j = 0; j < 4; ++j)
      bb[j] = *(const bf16x8*)&Fl[(ws*64 + j*16 + lr)*40 + g*8];
    #pragma unroll
    for (int i = 0; i < 4; ++i)
      #pragma unroll
      for (int j = 0; j < 4; ++j)
        acc[i][j] = __builtin_amdgcn_mfma_f32_16x16x32_bf16(af[i], bb[j], acc[i][j], 0, 0, 0);
  }

  #pragma unroll
  for (int i = 0; i < 4; ++i)
    #pragma unroll
    for (int r = 0; r < 4; ++r){
      const int co = wn*64 + i*16 + g*4 + r;
      const float bv = bias[co];
      #pragma unroll
      for (int j = 0; j < 4; ++j){
        const int s = s0 + ws*64 + j*16 + lr;
        if (s < L_) out[((size_t)b*COUT + co)*L_ + s] = acc[i][j][r] + bv;
      }
    }
}

extern "C" void kernel_launch(void* const* d_in, const int* in_sizes, int n_in,
                              void* d_out, int out_size, void* d_ws, size_t ws_size,
                              hipStream_t stream){
  const float* x      = (const float*)d_in[0];
  const float* weight = (const float*)d_in[1];
  const float* bias   = (const float*)d_in[2];
  const float* cc     = (const float*)d_in[3];
  const float* temp_p = (const float*)d_in[4];
  float* out = (float*)d_out;

  char* ws = (char*)d_ws;
  u16*   A   = (u16*)(ws);                 // N*P bf16   = 115,605,504 B
  u16*   S   = (u16*)(ws + 115605504);     // N*M bf16   =  51,380,224 B
  float* a2v = (float*)(ws + 166985728);   // N f32      =     401,408 B
  float* b2v = (float*)(ws + 167387136);   // 256 f32    =       1,024 B
  u16*   Cb  = (u16*)(ws + 167388160);     // 256x576 bf16 =   294,912 B
  u16*   Ct  = (u16*)(ws + 167683072);     // 576x256 bf16 =   294,912 B
  u16*   Wb  = (u16*)(ws + 167977984);     // 128x576 bf16 =   147,456 B

  k0_prep   <<<384,               256, 0, stream>>>(cc, weight, Cb, Ct, b2v, Wb);
  k1_unfold <<<N_/4,              256, 0, stream>>>(x, A, a2v);
  k2_assign <<<N_/64,             256, 0, stream>>>(A, Cb, a2v, b2v, temp_p, S);
  k3_transform<<<dim3(N_/128, 3), 384, 0, stream>>>(S, Ct, temp_p, A);
  k4_conv   <<<dim3(25, B_),      256, 0, stream>>>(A, Wb, bias, out);
}

// Round 4
// 332.595 us; speedup vs baseline: 3.6499x; 1.2001x over previous
//
#include <hip/hip_runtime.h>
#include <hip/hip_bf16.h>

#define B_    32
#define CIN   64
#define HW    56
#define COUT  128
#define M_    256
#define P_    576
#define L_    3136
#define N_    100352

typedef __hip_bfloat16 bf16;
typedef unsigned short u16;
typedef __attribute__((ext_vector_type(2))) unsigned short u16x2;
typedef __attribute__((ext_vector_type(8))) short bf16x8;
typedef __attribute__((ext_vector_type(8))) unsigned short u16x8;
typedef __attribute__((ext_vector_type(4))) float f32x4;

__device__ __forceinline__ float bits2f(u16 u){ return __uint_as_float(((unsigned)u) << 16); }
__device__ __forceinline__ u16 f2bf(float f){
  bf16 h = __float2bfloat16(f);
  return *(u16*)&h;
}
__device__ __forceinline__ void gload16(const void* g, void* l){
  __builtin_amdgcn_global_load_lds((const __attribute__((address_space(1))) void*)g,
                                   (__attribute__((address_space(3))) void*)l, 16, 0, 0);
}

// ---- K0: C -> Cb (bf16 [m][p]), Ct (bf16 [p][m]), b2; W -> Wb (bf16) -------
__global__ __launch_bounds__(256) void k0_prep(const float* __restrict__ C,
                                               const float* __restrict__ W,
                                               u16* __restrict__ Cb, u16* __restrict__ Ct,
                                               float* __restrict__ b2v, u16* __restrict__ Wb){
  __shared__ float red[4];
  const int t = threadIdx.x;
  const int bid = blockIdx.x;
  if (bid < M_){
    const int m = bid;
    float s = 0.f;
    for (int p = t; p < P_; p += 256){
      u16 h = f2bf(C[(size_t)m*P_ + p]);
      float vr = bits2f(h);
      s += vr*vr;
      Cb[(size_t)m*P_ + p] = h;
      Ct[(size_t)p*M_ + m] = h;
    }
    #pragma unroll
    for (int off = 32; off >= 1; off >>= 1) s += __shfl_xor(s, off);
    if ((t & 63) == 0) red[t >> 6] = s;
    __syncthreads();
    if (t == 0) b2v[m] = red[0] + red[1] + red[2] + red[3];
  } else {
    const int co = bid - M_;
    for (int q = t; q < P_; q += 256)
      Wb[(size_t)co*P_ + q] = f2bf(W[(size_t)co*P_ + q]);
  }
}

// ---- K1: unfold, tiled: block = (b,h); x window staged in LDS --------------
__global__ __launch_bounds__(256) void k1_unfold(const float* __restrict__ x,
                                                 u16* __restrict__ A,
                                                 float* __restrict__ a2v){
  __shared__ float xt[64*175 + 1];   // 64 ch x (3 rows x 58 cols), stride 175
  const int t = threadIdx.x;
  const int bid = blockIdx.x;
  const int b = bid / HW, h = bid % HW;

  // stage x window: coalesced along w
  for (int idx = t; idx < 64*174; idx += 256){
    const int c = idx / 174, rem = idx - c*174;
    const int r = rem / 58, wc = rem - r*58;
    const int iy = h + r - 1, ix = wc - 1;
    float v = 0.f;
    if ((unsigned)iy < (unsigned)HW && (unsigned)ix < (unsigned)HW)
      v = x[((size_t)b*CIN + c)*L_ + iy*HW + ix];
    xt[c*175 + r*58 + wc] = v;
  }
  __syncthreads();

  // A-write: lanes cover consecutive p (2 per lane), loop over 56 patches
  const int n0 = b*L_ + h*56;
  u16* Arow = A + (size_t)n0 * P_;
  #pragma unroll
  for (int k = 0; k < 2; ++k){
    const int pb = k*512 + t*2;
    if (pb < P_){
      const int c0 = pb/9,     rr0 = pb - c0*9;
      const int c1 = (pb+1)/9, rr1 = (pb+1) - c1*9;
      const float* s0 = &xt[c0*175 + (rr0/3)*58 + (rr0 - (rr0/3)*3)];
      const float* s1 = &xt[c1*175 + (rr1/3)*58 + (rr1 - (rr1/3)*3)];
      for (int w = 0; w < 56; ++w){
        u16x2 o = { f2bf(s0[w]), f2bf(s1[w]) };
        *(u16x2*)&Arow[(size_t)w*P_ + pb] = o;
      }
    }
  }

  // a2: wave per patch-subset, lane = channel
  const int wid = t >> 6, lane = t & 63;
  for (int w = wid; w < 56; w += 4){
    const float* src = &xt[lane*175 + w];
    float s = 0.f;
    #pragma unroll
    for (int r = 0; r < 3; ++r)
      #pragma unroll
      for (int dj = 0; dj < 3; ++dj){
        float vr = bits2f(f2bf(src[r*58 + dj]));
        s += vr*vr;
      }
    #pragma unroll
    for (int off = 32; off >= 1; off >>= 1) s += __shfl_xor(s, off);
    if (lane == 0) a2v[n0 + w] = s;
  }
}

// ---- K2: MFMA GEMM G=A*Cb^T (64n x 256m), fused dist+softmax -> S ----------
__global__ __launch_bounds__(256) void k2_assign(const u16* __restrict__ A,
    const u16* __restrict__ Cb, const float* __restrict__ a2v,
    const float* __restrict__ b2v, const float* __restrict__ temp_p,
    u16* __restrict__ S){
  __shared__ __align__(16) char lds2[64*264*2]; // 33792 B union
  short* Al = (short*)lds2;                     // 64*32  shorts (4 KB)
  short* Cl = (short*)(lds2 + 4096);            // 256*32 shorts (16 KB)
  float* red = (float*)lds2;                    // 256 floats (epilogue)
  u16*   Sl  = (u16*)lds2;                      // 64 x 264 (store staging)
  const int t = threadIdx.x;
  const int lane = t & 63;
  const int wm = t >> 6;
  const int g  = lane >> 4;
  const int lr = lane & 15;
  const int n0 = blockIdx.x * 64;
  const int sw = (g ^ (lr & 3)) << 3;

  f32x4 acc[4][4];
  #pragma unroll
  for (int i = 0; i < 4; ++i)
    #pragma unroll
    for (int j = 0; j < 4; ++j) acc[i][j] = (f32x4){0.f,0.f,0.f,0.f};

  const int arow = t >> 2, ach = t & 3;
  const int agch = ach ^ (arow & 3);

  for (int k0 = 0; k0 < P_; k0 += 32){
    __syncthreads();
    gload16(A + (size_t)(n0 + arow)*P_ + k0 + agch*8, &Al[t*8]);
    #pragma unroll
    for (int e = 0; e < 4; ++e){
      const int c = t + e*256;
      const int mr = c >> 2, ch = c & 3;
      gload16(Cb + (size_t)mr*P_ + k0 + (ch ^ (mr & 3))*8, &Cl[c*8]);
    }
    __syncthreads();
    bf16x8 af[4], bb[4];
    #pragma unroll
    for (int i = 0; i < 4; ++i)
      af[i] = *(const bf16x8*)&Al[(i*16 + lr)*32 + sw];
    #pragma unroll
    for (int j = 0; j < 4; ++j)
      bb[j] = *(const bf16x8*)&Cl[(wm*64 + j*16 + lr)*32 + sw];
    #pragma unroll
    for (int i = 0; i < 4; ++i)
      #pragma unroll
      for (int j = 0; j < 4; ++j)
        acc[i][j] = __builtin_amdgcn_mfma_f32_16x16x32_bf16(af[i], bb[j], acc[i][j], 0, 0, 0);
  }

  // epilogue: d = sqrt(a2+b2-2g) -> softmax over all 256 m
  const float temp = *temp_p;
  float a2r[4][4], b2r[4];
  #pragma unroll
  for (int i = 0; i < 4; ++i)
    #pragma unroll
    for (int r = 0; r < 4; ++r) a2r[i][r] = a2v[n0 + i*16 + g*4 + r];
  #pragma unroll
  for (int j = 0; j < 4; ++j) b2r[j] = b2v[wm*64 + j*16 + lr];

  float rmax[4][4];
  #pragma unroll
  for (int i = 0; i < 4; ++i)
    #pragma unroll
    for (int r = 0; r < 4; ++r) rmax[i][r] = -3.4e38f;

  #pragma unroll
  for (int i = 0; i < 4; ++i)
    #pragma unroll
    for (int j = 0; j < 4; ++j)
      #pragma unroll
      for (int r = 0; r < 4; ++r){
        float d2 = fmaxf(a2r[i][r] + b2r[j] - 2.f*acc[i][j][r], 1e-12f);
        float lg = -temp * sqrtf(d2);
        acc[i][j][r] = lg;
        rmax[i][r] = fmaxf(rmax[i][r], lg);
      }
  #pragma unroll
  for (int i = 0; i < 4; ++i)
    #pragma unroll
    for (int r = 0; r < 4; ++r){
      float v = rmax[i][r];
      v = fmaxf(v, __shfl_xor(v, 1));
      v = fmaxf(v, __shfl_xor(v, 2));
      v = fmaxf(v, __shfl_xor(v, 4));
      v = fmaxf(v, __shfl_xor(v, 8));
      rmax[i][r] = v;
    }
  __syncthreads();
  if (lr == 0){
    #pragma unroll
    for (int i = 0; i < 4; ++i)
      #pragma unroll
      for (int r = 0; r < 4; ++r) red[wm*64 + i*16 + g*4 + r] = rmax[i][r];
  }
  __syncthreads();
  #pragma unroll
  for (int i = 0; i < 4; ++i)
    #pragma unroll
    for (int r = 0; r < 4; ++r){
      const int row = i*16 + g*4 + r;
      rmax[i][r] = fmaxf(fmaxf(red[row], red[64+row]), fmaxf(red[128+row], red[192+row]));
    }
  float rsum[4][4];
  #pragma unroll
  for (int i = 0; i < 4; ++i)
    #pragma unroll
    for (int r = 0; r < 4; ++r) rsum[i][r] = 0.f;
  #pragma unroll
  for (int i = 0; i < 4; ++i)
    #pragma unroll
    for (int j = 0; j < 4; ++j)
      #pragma unroll
      for (int r = 0; r < 4; ++r){
        float pe = __expf(acc[i][j][r] - rmax[i][r]);
        acc[i][j][r] = pe;
        rsum[i][r] += pe;
      }
  #pragma unroll
  for (int i = 0; i < 4; ++i)
    #pragma unroll
    for (int r = 0; r < 4; ++r){
      float v = rsum[i][r];
      v += __shfl_xor(v, 1);
      v += __shfl_xor(v, 2);
      v += __shfl_xor(v, 4);
      v += __shfl_xor(v, 8);
      rsum[i][r] = v;
    }
  __syncthreads();
  if (lr == 0){
    #pragma unroll
    for (int i = 0; i < 4; ++i)
      #pragma unroll
      for (int r = 0; r < 4; ++r) red[wm*64 + i*16 + g*4 + r] = rsum[i][r];
  }
  __syncthreads();
  float invr[4][4];
  #pragma unroll
  for (int i = 0; i < 4; ++i)
    #pragma unroll
    for (int r = 0; r < 4; ++r){
      const int row = i*16 + g*4 + r;
      invr[i][r] = 1.f / (red[row] + red[64+row] + red[128+row] + red[192+row]);
    }
  __syncthreads();   // red reads done; LDS free for Sl
  #pragma unroll
  for (int i = 0; i < 4; ++i)
    #pragma unroll
    for (int r = 0; r < 4; ++r)
      #pragma unroll
      for (int j = 0; j < 4; ++j)
        Sl[(i*16 + g*4 + r)*264 + wm*64 + j*16 + lr] = f2bf(acc[i][j][r] * invr[i][r]);
  __syncthreads();
  for (int v = t; v < 64*32; v += 256){
    const int row = v >> 5, col = v & 31;
    u16x8 d = *(const u16x8*)&Sl[row*264 + col*8];
    *(u16x8*)(S + (size_t)(n0 + row)*M_ + col*8) = d;
  }
}

// ---- K3: MFMA GEMM T=S*C (128n x 192p), skip fused in coalesced store ------
__global__ __launch_bounds__(384) void k3_transform(const u16* __restrict__ S,
    const u16* __restrict__ Ct, const float* __restrict__ temp_p,
    u16* __restrict__ AF){
  __shared__ __align__(16) char lds3[128*200*2]; // 51200 B union
  short* Sl  = (short*)lds3;                     // 128*32 shorts (8 KB)
  short* Ctl = (short*)(lds3 + 8192);            // 192*32 shorts (12 KB)
  u16*   Fl  = (u16*)lds3;                       // 128 x 200 (store staging)
  const int t = threadIdx.x;
  const int lane = t & 63;
  const int w = t >> 6;           // 0..5
  const int wn = w / 3;           // 0..1
  const int wp = w - wn*3;        // 0..2
  const int g  = lane >> 4;
  const int lr = lane & 15;
  const int n0 = blockIdx.x * 128;
  const int p0 = blockIdx.y * 192;
  const int sw = (g ^ (lr & 3)) << 3;

  f32x4 acc[4][4];
  #pragma unroll
  for (int i = 0; i < 4; ++i)
    #pragma unroll
    for (int j = 0; j < 4; ++j) acc[i][j] = (f32x4){0.f,0.f,0.f,0.f};

  for (int k0 = 0; k0 < M_; k0 += 32){
    __syncthreads();
    { const int c = t;           const int r = c >> 2, ch = c & 3;
      gload16(S + (size_t)(n0 + r)*M_ + k0 + (ch ^ (r & 3))*8, &Sl[c*8]); }
    if (t < 128){
      const int c = t + 384;     const int r = c >> 2, ch = c & 3;
      gload16(S + (size_t)(n0 + r)*M_ + k0 + (ch ^ (r & 3))*8, &Sl[c*8]); }
    #pragma unroll
    for (int e = 0; e < 2; ++e){
      const int c = t + e*384;
      const int r = c >> 2, ch = c & 3;
      gload16(Ct + (size_t)(p0 + r)*M_ + k0 + (ch ^ (r & 3))*8, &Ctl[c*8]);
    }
    __syncthreads();
    bf16x8 af[4], bb[4];
    #pragma unroll
    for (int i = 0; i < 4; ++i)
      af[i] = *(const bf16x8*)&Sl[(wn*64 + i*16 + lr)*32 + sw];
    #pragma unroll
    for (int j = 0; j < 4; ++j)
      bb[j] = *(const bf16x8*)&Ctl[(wp*64 + j*16 + lr)*32 + sw];
    #pragma unroll
    for (int i = 0; i < 4; ++i)
      #pragma unroll
      for (int j = 0; j < 4; ++j)
        acc[i][j] = __builtin_amdgcn_mfma_f32_16x16x32_bf16(af[i], bb[j], acc[i][j], 0, 0, 0);
  }

  const float temp = *temp_p;
  const float inv = 1.f / (temp + 1.f);
  const float tscale = temp * inv;
  __syncthreads();   // staging reads done; LDS free for Fl
  #pragma unroll
  for (int i = 0; i < 4; ++i)
    #pragma unroll
    for (int r = 0; r < 4; ++r)
      #pragma unroll
      for (int j = 0; j < 4; ++j)
        Fl[(wn*64 + i*16 + g*4 + r)*200 + wp*64 + j*16 + lr] = f2bf(acc[i][j][r] * tscale);
  __syncthreads();
  for (int v = t; v < 128*24; v += 384){
    const int row = v / 24, col = v - row*24;
    u16x8 tv = *(const u16x8*)&Fl[row*200 + col*8];
    u16* gp = AF + (size_t)(n0 + row)*P_ + p0 + col*8;
    u16x8 av = *(const u16x8*)gp;
    u16x8 o;
    #pragma unroll
    for (int e = 0; e < 8; ++e)
      o[e] = f2bf(bits2f(tv[e]) + bits2f(av[e]) * inv);
    *(u16x8*)gp = o;
  }
}

// ---- K4: MFMA GEMM out = Wb * F (+bias), mask fused into F staging ---------
__global__ __launch_bounds__(256) void k4_conv(const u16* __restrict__ F,
    const u16* __restrict__ Wb, const float* __restrict__ bias,
    float* __restrict__ out){
  __shared__ short Wl[128*32];    // 8 KB
  __shared__ short Fl[128*40];    // 10 KB, row stride 40 shorts (16B aligned)
  const int t = threadIdx.x;
  const int lane = t & 63;
  const int w = t >> 6;           // 0..3
  const int wn = w >> 1;          // co half
  const int ws = w & 1;           // s half
  const int g  = lane >> 4;
  const int lr = lane & 15;
  const int b  = blockIdx.y;
  const int s0 = blockIdx.x * 128;
  const int sw = (g ^ (lr & 3)) << 3;
  const u16* Fb = F + (size_t)b * ((size_t)P_ * L_);

  f32x4 acc[4][4];
  #pragma unroll
  for (int i = 0; i < 4; ++i)
    #pragma unroll
    for (int j = 0; j < 4; ++j) acc[i][j] = (f32x4){0.f,0.f,0.f,0.f};

  for (int q0 = 0; q0 < P_; q0 += 32){
    __syncthreads();
    #pragma unroll
    for (int e = 0; e < 2; ++e){
      const int c = t + e*256;
      const int r = c >> 2, ch = c & 3;
      gload16(Wb + (size_t)r*P_ + q0 + (ch ^ (r & 3))*8, &Wl[c*8]);
    }
    #pragma unroll
    for (int e = 0; e < 2; ++e){
      const int c = t + e*256;
      const int ql = c & 31, sch = c >> 5;
      const int q  = q0 + ql;
      const int sbase = s0 + sch*8;
      const int scl = (sbase < L_ - 8) ? sbase : (L_ - 8);
      u16x8 v = *(const u16x8*)(Fb + (size_t)q*L_ + scl);
      const int q3 = q/3;
      const bool kx0 = (q - q3*3) == 0;
      const bool ky0 = (q3 % 3) == 0;
      const int r0 = sbase % 56;
      #pragma unroll
      for (int u = 0; u < 8; ++u){
        const bool m0 = ky0 && (sbase + u) < 56;
        const bool m1 = kx0 && ((r0 + u) == 0 || (r0 + u) == 56);
        Fl[(sch*8 + u)*40 + ql] = (m0 || m1) ? (short)0 : (short)v[u];
      }
    }
    __syncthreads();
    bf16x8 af[4], bb[4];
    #pragma unroll
    for (int i = 0; i < 4; ++i)
      af[i] = *(const bf16x8*)&Wl[(wn*64 + i*16 + lr)*32 + sw];
    #pragma unroll
    for (int j = 0; j < 4; ++j)
      bb[j] = *(const bf16x8*)&Fl[(ws*64 + j*16 + lr)*40 + g*8];
    #pragma unroll
    for (int i = 0; i < 4; ++i)
      #pragma unroll
      for (int j = 0; j < 4; ++j)
        acc[i][j] = __builtin_amdgcn_mfma_f32_16x16x32_bf16(af[i], bb[j], acc[i][j], 0, 0, 0);
  }

  #pragma unroll
  for (int i = 0; i < 4; ++i)
    #pragma unroll
    for (int r = 0; r < 4; ++r){
      const int co = wn*64 + i*16 + g*4 + r;
      const float bv = bias[co];
      #pragma unroll
      for (int j = 0; j < 4; ++j){
        const int s = s0 + ws*64 + j*16 + lr;
        if (s < L_) out[((size_t)b*COUT + co)*L_ + s] = acc[i][j][r] + bv;
      }
    }
}

extern "C" void kernel_launch(void* const* d_in, const int* in_sizes, int n_in,
                              void* d_out, int out_size, void* d_ws, size_t ws_size,
                              hipStream_t stream){
  const float* x      = (const float*)d_in[0];
  const float* weight = (const float*)d_in[1];
  const float* bias   = (const float*)d_in[2];
  const float* cc     = (const float*)d_in[3];
  const float* temp_p = (const float*)d_in[4];
  float* out = (float*)d_out;

  char* ws = (char*)d_ws;
  u16*   A   = (u16*)(ws);                 // N*P bf16   = 115,605,504 B
  u16*   S   = (u16*)(ws + 115605504);     // N*M bf16   =  51,380,224 B
  float* a2v = (float*)(ws + 166985728);   // N f32      =     401,408 B
  float* b2v = (float*)(ws + 167387136);   // 256 f32    =       1,024 B
  u16*   Cb  = (u16*)(ws + 167388160);     // 256x576 bf16 =   294,912 B
  u16*   Ct  = (u16*)(ws + 167683072);     // 576x256 bf16 =   294,912 B
  u16*   Wb  = (u16*)(ws + 167977984);     // 128x576 bf16 =   147,456 B

  k0_prep   <<<384,               256, 0, stream>>>(cc, weight, Cb, Ct, b2v, Wb);
  k1_unfold <<<B_*HW,             256, 0, stream>>>(x, A, a2v);
  k2_assign <<<N_/64,             256, 0, stream>>>(A, Cb, a2v, b2v, temp_p, S);
  k3_transform<<<dim3(N_/128, 3), 384, 0, stream>>>(S, Ct, temp_p, A);
  k4_conv   <<<dim3(25, B_),      256, 0, stream>>>(A, Wb, bias, out);
}

// Round 5
// 299.932 us; speedup vs baseline: 4.0473x; 1.1089x over previous
//
#include <hip/hip_runtime.h>
#include <hip/hip_bf16.h>

#define B_    32
#define CIN   64
#define HW    56
#define COUT  128
#define M_    256
#define P_    576
#define L_    3136
#define N_    100352

typedef __hip_bfloat16 bf16;
typedef unsigned short u16;
typedef __attribute__((ext_vector_type(2))) unsigned short u16x2;
typedef __attribute__((ext_vector_type(8))) short bf16x8;
typedef __attribute__((ext_vector_type(8))) unsigned short u16x8;
typedef __attribute__((ext_vector_type(4))) float f32x4;

__device__ __forceinline__ float bits2f(u16 u){ return __uint_as_float(((unsigned)u) << 16); }
__device__ __forceinline__ u16 f2bf(float f){
  bf16 h = __float2bfloat16(f);
  return *(u16*)&h;
}
__device__ __forceinline__ void gload16(const void* g, void* l){
  __builtin_amdgcn_global_load_lds((const __attribute__((address_space(1))) void*)g,
                                   (__attribute__((address_space(3))) void*)l, 16, 0, 0);
}

// ---- K0: C -> Cb (bf16 [m][p]), Ct (bf16 [p][m]), b2; W -> Wb (bf16) -------
__global__ __launch_bounds__(256) void k0_prep(const float* __restrict__ C,
                                               const float* __restrict__ W,
                                               u16* __restrict__ Cb, u16* __restrict__ Ct,
                                               float* __restrict__ b2v, u16* __restrict__ Wb){
  __shared__ float red[4];
  const int t = threadIdx.x;
  const int bid = blockIdx.x;
  if (bid < M_){
    const int m = bid;
    float s = 0.f;
    for (int p = t; p < P_; p += 256){
      u16 h = f2bf(C[(size_t)m*P_ + p]);
      float vr = bits2f(h);
      s += vr*vr;
      Cb[(size_t)m*P_ + p] = h;
      Ct[(size_t)p*M_ + m] = h;
    }
    #pragma unroll
    for (int off = 32; off >= 1; off >>= 1) s += __shfl_xor(s, off);
    if ((t & 63) == 0) red[t >> 6] = s;
    __syncthreads();
    if (t == 0) b2v[m] = red[0] + red[1] + red[2] + red[3];
  } else {
    const int co = bid - M_;
    for (int q = t; q < P_; q += 256)
      Wb[(size_t)co*P_ + q] = f2bf(W[(size_t)co*P_ + q]);
  }
}

// ---- K1: unfold, tiled: block = (b,h); x window staged in LDS --------------
__global__ __launch_bounds__(256) void k1_unfold(const float* __restrict__ x,
                                                 u16* __restrict__ A,
                                                 float* __restrict__ a2v){
  __shared__ float xt[64*175 + 1];   // 64 ch x (3 rows x 58 cols), stride 175
  const int t = threadIdx.x;
  const int bid = blockIdx.x;
  const int b = bid / HW, h = bid % HW;

  // stage x window: coalesced along w
  for (int idx = t; idx < 64*174; idx += 256){
    const int c = idx / 174, rem = idx - c*174;
    const int r = rem / 58, wc = rem - r*58;
    const int iy = h + r - 1, ix = wc - 1;
    float v = 0.f;
    if ((unsigned)iy < (unsigned)HW && (unsigned)ix < (unsigned)HW)
      v = x[((size_t)b*CIN + c)*L_ + iy*HW + ix];
    xt[c*175 + r*58 + wc] = v;
  }
  __syncthreads();

  // A-write: lanes cover consecutive p (2 per lane), loop over 56 patches
  const int n0 = b*L_ + h*56;
  u16* Arow = A + (size_t)n0 * P_;
  #pragma unroll
  for (int k = 0; k < 2; ++k){
    const int pb = k*512 + t*2;
    if (pb < P_){
      const int c0 = pb/9,     rr0 = pb - c0*9;
      const int c1 = (pb+1)/9, rr1 = (pb+1) - c1*9;
      const float* s0 = &xt[c0*175 + (rr0/3)*58 + (rr0 - (rr0/3)*3)];
      const float* s1 = &xt[c1*175 + (rr1/3)*58 + (rr1 - (rr1/3)*3)];
      for (int w = 0; w < 56; ++w){
        u16x2 o = { f2bf(s0[w]), f2bf(s1[w]) };
        *(u16x2*)&Arow[(size_t)w*P_ + pb] = o;
      }
    }
  }

  // a2: wave per patch-subset, lane = channel
  const int wid = t >> 6, lane = t & 63;
  for (int w = wid; w < 56; w += 4){
    const float* src = &xt[lane*175 + w];
    float s = 0.f;
    #pragma unroll
    for (int r = 0; r < 3; ++r)
      #pragma unroll
      for (int dj = 0; dj < 3; ++dj){
        float vr = bits2f(f2bf(src[r*58 + dj]));
        s += vr*vr;
      }
    #pragma unroll
    for (int off = 32; off >= 1; off >>= 1) s += __shfl_xor(s, off);
    if (lane == 0) a2v[n0 + w] = s;
  }
}

// ---- K23: fused assign+transform. Block = 64 rows n, softmax S stays in LDS.
// Phase 1: G = A*Cb^T (64x256), dist+softmax -> Sl (LDS).
// Phase 2: T = Sl*Ct (64x576), skip-RMW into AF.
__global__ __launch_bounds__(256, 2) void k23_fused(const u16* __restrict__ A,
    const u16* __restrict__ Cb, const u16* __restrict__ Ct,
    const float* __restrict__ a2v, const float* __restrict__ b2v,
    const float* __restrict__ temp_p, u16* __restrict__ AF){
  __shared__ __align__(16) char lds[72704];
  u16*   Sl  = (u16*)lds;             // 64 x 264 u16 = 33792 B (persistent)
  char*  R2  = lds + 33792;           // 38912 B staging union
  short* Al  = (short*)R2;            // 64*32 shorts (phase 1)
  short* Cl  = (short*)(R2 + 4096);   // 256*32 shorts (phase 1)
  float* red = (float*)R2;            // 256 f (softmax)
  short* CtL = (short*)R2;            // 576*32 shorts (phase 2)
  u16*   Fl  = (u16*)R2;              // 64 x 296 u16 (F staging)

  const int t = threadIdx.x;
  const int lane = t & 63;
  const int wv = t >> 6;              // wave 0..3
  const int g  = lane >> 4;
  const int lr = lane & 15;
  const int n0 = blockIdx.x * 64;
  const int sw = (g ^ (lr & 3)) << 3;
  const float temp = *temp_p;

  // ================= phase 1: G = A * Cb^T =================
  f32x4 acc[4][4];
  #pragma unroll
  for (int i = 0; i < 4; ++i)
    #pragma unroll
    for (int j = 0; j < 4; ++j) acc[i][j] = (f32x4){0.f,0.f,0.f,0.f};

  const int arow = t >> 2, ach = t & 3;
  const int agch = ach ^ (arow & 3);

  for (int k0 = 0; k0 < P_; k0 += 32){
    __syncthreads();
    gload16(A + (size_t)(n0 + arow)*P_ + k0 + agch*8, &Al[t*8]);
    #pragma unroll
    for (int e = 0; e < 4; ++e){
      const int c = t + e*256;
      const int mr = c >> 2, ch = c & 3;
      gload16(Cb + (size_t)mr*P_ + k0 + (ch ^ (mr & 3))*8, &Cl[c*8]);
    }
    __syncthreads();
    bf16x8 af[4], bb[4];
    #pragma unroll
    for (int i = 0; i < 4; ++i)
      af[i] = *(const bf16x8*)&Al[(i*16 + lr)*32 + sw];
    #pragma unroll
    for (int j = 0; j < 4; ++j)
      bb[j] = *(const bf16x8*)&Cl[(wv*64 + j*16 + lr)*32 + sw];
    #pragma unroll
    for (int i = 0; i < 4; ++i)
      #pragma unroll
      for (int j = 0; j < 4; ++j)
        acc[i][j] = __builtin_amdgcn_mfma_f32_16x16x32_bf16(af[i], bb[j], acc[i][j], 0, 0, 0);
  }

  // ---- softmax over all 256 m ----
  float a2r[4][4], b2r[4];
  #pragma unroll
  for (int i = 0; i < 4; ++i)
    #pragma unroll
    for (int r = 0; r < 4; ++r) a2r[i][r] = a2v[n0 + i*16 + g*4 + r];
  #pragma unroll
  for (int j = 0; j < 4; ++j) b2r[j] = b2v[wv*64 + j*16 + lr];

  float rmax[4][4];
  #pragma unroll
  for (int i = 0; i < 4; ++i)
    #pragma unroll
    for (int r = 0; r < 4; ++r) rmax[i][r] = -3.4e38f;

  #pragma unroll
  for (int i = 0; i < 4; ++i)
    #pragma unroll
    for (int j = 0; j < 4; ++j)
      #pragma unroll
      for (int r = 0; r < 4; ++r){
        float d2 = fmaxf(a2r[i][r] + b2r[j] - 2.f*acc[i][j][r], 1e-12f);
        float lg = -temp * sqrtf(d2);
        acc[i][j][r] = lg;
        rmax[i][r] = fmaxf(rmax[i][r], lg);
      }
  #pragma unroll
  for (int i = 0; i < 4; ++i)
    #pragma unroll
    for (int r = 0; r < 4; ++r){
      float v = rmax[i][r];
      v = fmaxf(v, __shfl_xor(v, 1));
      v = fmaxf(v, __shfl_xor(v, 2));
      v = fmaxf(v, __shfl_xor(v, 4));
      v = fmaxf(v, __shfl_xor(v, 8));
      rmax[i][r] = v;
    }
  __syncthreads();                 // phase-1 LDS reads done
  if (lr == 0){
    #pragma unroll
    for (int i = 0; i < 4; ++i)
      #pragma unroll
      for (int r = 0; r < 4; ++r) red[wv*64 + i*16 + g*4 + r] = rmax[i][r];
  }
  __syncthreads();
  #pragma unroll
  for (int i = 0; i < 4; ++i)
    #pragma unroll
    for (int r = 0; r < 4; ++r){
      const int row = i*16 + g*4 + r;
      rmax[i][r] = fmaxf(fmaxf(red[row], red[64+row]), fmaxf(red[128+row], red[192+row]));
    }
  float rsum[4][4];
  #pragma unroll
  for (int i = 0; i < 4; ++i)
    #pragma unroll
    for (int r = 0; r < 4; ++r) rsum[i][r] = 0.f;
  #pragma unroll
  for (int i = 0; i < 4; ++i)
    #pragma unroll
    for (int j = 0; j < 4; ++j)
      #pragma unroll
      for (int r = 0; r < 4; ++r){
        float pe = __expf(acc[i][j][r] - rmax[i][r]);
        acc[i][j][r] = pe;
        rsum[i][r] += pe;
      }
  #pragma unroll
  for (int i = 0; i < 4; ++i)
    #pragma unroll
    for (int r = 0; r < 4; ++r){
      float v = rsum[i][r];
      v += __shfl_xor(v, 1);
      v += __shfl_xor(v, 2);
      v += __shfl_xor(v, 4);
      v += __shfl_xor(v, 8);
      rsum[i][r] = v;
    }
  __syncthreads();                 // rmax reads done
  if (lr == 0){
    #pragma unroll
    for (int i = 0; i < 4; ++i)
      #pragma unroll
      for (int r = 0; r < 4; ++r) red[wv*64 + i*16 + g*4 + r] = rsum[i][r];
  }
  __syncthreads();
  #pragma unroll
  for (int i = 0; i < 4; ++i)
    #pragma unroll
    for (int r = 0; r < 4; ++r){
      const int row = i*16 + g*4 + r;
      const float invr = 1.f / (red[row] + red[64+row] + red[128+row] + red[192+row]);
      #pragma unroll
      for (int j = 0; j < 4; ++j)
        Sl[(size_t)row*264 + wv*64 + j*16 + lr] = f2bf(acc[i][j][r] * invr);
    }
  __syncthreads();                 // Sl visible; red reads done (R2 reusable)

  // ================= phase 2: T = Sl * Ct =================
  const int p0q = wv * 144;        // wave's p-quarter
  f32x4 acc2[4][9];
  #pragma unroll
  for (int i = 0; i < 4; ++i)
    #pragma unroll
    for (int j = 0; j < 9; ++j) acc2[i][j] = (f32x4){0.f,0.f,0.f,0.f};

  for (int mc = 0; mc < 8; ++mc){
    if (mc) __syncthreads();
    #pragma unroll
    for (int e = 0; e < 9; ++e){
      const int c = t + e*256;     // 0..2303
      const int pr = c >> 2, ch = c & 3;
      gload16(Ct + (size_t)pr*M_ + mc*32 + ((ch ^ (pr & 3))<<3), &CtL[c*8]);
    }
    __syncthreads();
    bf16x8 af2[4];
    #pragma unroll
    for (int i = 0; i < 4; ++i)
      af2[i] = *(const bf16x8*)&Sl[(size_t)(i*16 + lr)*264 + mc*32 + g*8];
    #pragma unroll
    for (int j = 0; j < 9; ++j){
      bf16x8 bb = *(const bf16x8*)&CtL[(p0q + j*16 + lr)*32 + sw];
      #pragma unroll
      for (int i = 0; i < 4; ++i)
        acc2[i][j] = __builtin_amdgcn_mfma_f32_16x16x32_bf16(af2[i], bb, acc2[i][j], 0, 0, 0);
    }
  }
  __syncthreads();                 // CtL reads done (R2 -> Fl)

  // ---- F write: two 288-p halves, skip-RMW coalesced ----
  const float inv = 1.f / (temp + 1.f);
  const float tscale = temp * inv;
  #pragma unroll
  for (int h = 0; h < 2; ++h){
    if ((wv >> 1) == h){
      const int pbase = (wv & 1) * 144;
      #pragma unroll
      for (int i = 0; i < 4; ++i)
        #pragma unroll
        for (int j = 0; j < 9; ++j)
          #pragma unroll
          for (int r = 0; r < 4; ++r)
            Fl[(i*16 + g*4 + r)*296 + pbase + j*16 + lr] = f2bf(acc2[i][j][r] * tscale);
    }
    __syncthreads();
    #pragma unroll
    for (int e = 0; e < 9; ++e){
      const int v = t + e*256;     // 0..2303
      const int row = v / 36, col = (v - row*36) * 8;
      u16x8 tv = *(const u16x8*)&Fl[row*296 + col];
      u16* gp = AF + (size_t)(n0 + row)*P_ + h*288 + col;
      u16x8 av = *(const u16x8*)gp;
      u16x8 o;
      #pragma unroll
      for (int e2 = 0; e2 < 8; ++e2)
        o[e2] = f2bf(bits2f(tv[e2]) + bits2f(av[e2]) * inv);
      *(u16x8*)gp = o;
    }
    __syncthreads();
  }
}

// ---- K4: MFMA GEMM out = Wb * F (+bias), mask fused into F staging ---------
__global__ __launch_bounds__(256) void k4_conv(const u16* __restrict__ F,
    const u16* __restrict__ Wb, const float* __restrict__ bias,
    float* __restrict__ out){
  __shared__ short Wl[128*32];    // 8 KB
  __shared__ short Fl[128*40];    // 10 KB, row stride 40 shorts (16B aligned)
  const int t = threadIdx.x;
  const int lane = t & 63;
  const int w = t >> 6;           // 0..3
  const int wn = w >> 1;          // co half
  const int ws = w & 1;           // s half
  const int g  = lane >> 4;
  const int lr = lane & 15;
  const int b  = blockIdx.y;
  const int s0 = blockIdx.x * 128;
  const int sw = (g ^ (lr & 3)) << 3;
  const u16* Fb = F + (size_t)b * ((size_t)P_ * L_);

  f32x4 acc[4][4];
  #pragma unroll
  for (int i = 0; i < 4; ++i)
    #pragma unroll
    for (int j = 0; j < 4; ++j) acc[i][j] = (f32x4){0.f,0.f,0.f,0.f};

  for (int q0 = 0; q0 < P_; q0 += 32){
    __syncthreads();
    #pragma unroll
    for (int e = 0; e < 2; ++e){
      const int c = t + e*256;
      const int r = c >> 2, ch = c & 3;
      gload16(Wb + (size_t)r*P_ + q0 + (ch ^ (r & 3))*8, &Wl[c*8]);
    }
    #pragma unroll
    for (int e = 0; e < 2; ++e){
      const int c = t + e*256;
      const int ql = c & 31, sch = c >> 5;
      const int q  = q0 + ql;
      const int sbase = s0 + sch*8;
      const int scl = (sbase < L_ - 8) ? sbase : (L_ - 8);
      u16x8 v = *(const u16x8*)(Fb + (size_t)q*L_ + scl);
      const int q3 = q/3;
      const bool kx0 = (q - q3*3) == 0;
      const bool ky0 = (q3 % 3) == 0;
      const int r0 = sbase % 56;
      #pragma unroll
      for (int u = 0; u < 8; ++u){
        const bool m0 = ky0 && (sbase + u) < 56;
        const bool m1 = kx0 && ((r0 + u) == 0 || (r0 + u) == 56);
        Fl[(sch*8 + u)*40 + ql] = (m0 || m1) ? (short)0 : (short)v[u];
      }
    }
    __syncthreads();
    bf16x8 af[4], bb[4];
    #pragma unroll
    for (int i = 0; i < 4; ++i)
      af[i] = *(const bf16x8*)&Wl[(wn*64 + i*16 + lr)*32 + sw];
    #pragma unroll
    for (int j = 0; j < 4; ++j)
      bb[j] = *(const bf16x8*)&Fl[(ws*64 + j*16 + lr)*40 + g*8];
    #pragma unroll
    for (int i = 0; i < 4; ++i)
      #pragma unroll
      for (int j = 0; j < 4; ++j)
        acc[i][j] = __builtin_amdgcn_mfma_f32_16x16x32_bf16(af[i], bb[j], acc[i][j], 0, 0, 0);
  }

  #pragma unroll
  for (int i = 0; i < 4; ++i)
    #pragma unroll
    for (int r = 0; r < 4; ++r){
      const int co = wn*64 + i*16 + g*4 + r;
      const float bv = bias[co];
      #pragma unroll
      for (int j = 0; j < 4; ++j){
        const int s = s0 + ws*64 + j*16 + lr;
        if (s < L_) out[((size_t)b*COUT + co)*L_ + s] = acc[i][j][r] + bv;
      }
    }
}

extern "C" void kernel_launch(void* const* d_in, const int* in_sizes, int n_in,
                              void* d_out, int out_size, void* d_ws, size_t ws_size,
                              hipStream_t stream){
  const float* x      = (const float*)d_in[0];
  const float* weight = (const float*)d_in[1];
  const float* bias   = (const float*)d_in[2];
  const float* cc     = (const float*)d_in[3];
  const float* temp_p = (const float*)d_in[4];
  float* out = (float*)d_out;

  char* ws = (char*)d_ws;
  u16*   A   = (u16*)(ws);                 // N*P bf16   = 115,605,504 B
  float* a2v = (float*)(ws + 166985728);   // N f32      =     401,408 B
  float* b2v = (float*)(ws + 167387136);   // 256 f32    =       1,024 B
  u16*   Cb  = (u16*)(ws + 167388160);     // 256x576 bf16 =   294,912 B
  u16*   Ct  = (u16*)(ws + 167683072);     // 576x256 bf16 =   294,912 B
  u16*   Wb  = (u16*)(ws + 167977984);     // 128x576 bf16 =   147,456 B

  k0_prep   <<<384,          256, 0, stream>>>(cc, weight, Cb, Ct, b2v, Wb);
  k1_unfold <<<B_*HW,        256, 0, stream>>>(x, A, a2v);
  k23_fused <<<N_/64,        256, 0, stream>>>(A, Cb, Ct, a2v, b2v, temp_p, A);
  k4_conv   <<<dim3(25, B_), 256, 0, stream>>>(A, Wb, bias, out);
}